// Round 5
// baseline (26.561 us; speedup 1.0000x reference)
//
#include <hip/hip_runtime.h>

typedef float f32x4 __attribute__((ext_vector_type(4)));

constexpr int B_ = 8, L_ = 2048, N_ = 64;
constexpr int RPW = 2;            // rows per wave
constexpr int THREADS = 256;      // 4 waves per block
constexpr int RPB = RPW * 4;      // 8 rows per block

__global__ __launch_bounds__(THREADS, 5) void attn_all(
    const float* __restrict__ query, const float* __restrict__ key,
    const float* __restrict__ value, const float* __restrict__ Wp,
    const float* __restrict__ bp, float* __restrict__ attended,
    float* __restrict__ weights)
{
    const int tid  = threadIdx.x;
    const int lane = tid & 63;
    const int wave = tid >> 6;

    constexpr int BPB = L_ / RPB;                 // 256 blocks per batch
    const int b  = blockIdx.x / BPB;
    const int q0 = (blockIdx.x % BPB) * RPB + wave * RPW;

    const f32x4* K4 = reinterpret_cast<const f32x4*>(key + b * L_);
    const f32x4* V4 = reinterpret_cast<const f32x4*>(value + b * L_);

    // K and V rows live in registers (8 KB each per wave).
    f32x4 kk[8], vv[8];
    #pragma unroll
    for (int i = 0; i < 8; ++i) { kk[i] = K4[lane + 64 * i]; vv[i] = V4[lane + 64 * i]; }

    // Prefetch the two query scalars early.
    const int rowA = b * L_ + q0;
    const int rowB = rowA + 1;
    const float QA = query[rowA];
    const float QB = query[rowB];

    // s2 = sum W^2, sb = sum W*b   (interleaved with kmax/kmin butterflies)
    const float w_l = Wp[lane];
    const float b_l = bp[lane];
    float s2 = w_l * w_l, sb = w_l * b_l;

    float kmax = -3.4e38f, kmin = 3.4e38f;
    #pragma unroll
    for (int i = 0; i < 8; ++i) {
        kmax = fmaxf(kmax, fmaxf(fmaxf(kk[i].x, kk[i].y), fmaxf(kk[i].z, kk[i].w)));
        kmin = fminf(kmin, fminf(fminf(kk[i].x, kk[i].y), fminf(kk[i].z, kk[i].w)));
    }
    #pragma unroll
    for (int off = 32; off; off >>= 1) {
        s2   += __shfl_xor(s2, off);
        sb   += __shfl_xor(sb, off);
        kmax  = fmaxf(kmax, __shfl_xor(kmax, off));
        kmin  = fminf(kmin, __shfl_xor(kmin, off));
    }

    const float LOG2E = 1.4426950408889634f;

    const float alphaA = fmaf(QA, s2, sb);
    const float c1A    = alphaA * LOG2E;
    const float m2A    = (alphaA > 0.f ? alphaA * kmax : alphaA * kmin) * LOG2E;
    const float alphaB = fmaf(QB, s2, sb);
    const float c1B    = alphaB * LOG2E;
    const float m2B    = (alphaB > 0.f ? alphaB * kmax : alphaB * kmin) * LOG2E;

    // ---- stats for both rows (independent chains; p NOT kept) ----
    float sumA = 0.f, pvA = 0.f, sumB = 0.f, pvB = 0.f;
    #pragma unroll
    for (int i = 0; i < 8; ++i) {
        float a0 = __builtin_amdgcn_exp2f(fmaf(c1A, kk[i].x, -m2A));
        float a1 = __builtin_amdgcn_exp2f(fmaf(c1A, kk[i].y, -m2A));
        float a2 = __builtin_amdgcn_exp2f(fmaf(c1A, kk[i].z, -m2A));
        float a3 = __builtin_amdgcn_exp2f(fmaf(c1A, kk[i].w, -m2A));
        sumA += (a0 + a1) + (a2 + a3);
        pvA  += (a0 * vv[i].x + a1 * vv[i].y) + (a2 * vv[i].z + a3 * vv[i].w);
        float b0 = __builtin_amdgcn_exp2f(fmaf(c1B, kk[i].x, -m2B));
        float b1 = __builtin_amdgcn_exp2f(fmaf(c1B, kk[i].y, -m2B));
        float b2 = __builtin_amdgcn_exp2f(fmaf(c1B, kk[i].z, -m2B));
        float b3 = __builtin_amdgcn_exp2f(fmaf(c1B, kk[i].w, -m2B));
        sumB += (b0 + b1) + (b2 + b3);
        pvB  += (b0 * vv[i].x + b1 * vv[i].y) + (b2 * vv[i].z + b3 * vv[i].w);
    }
    #pragma unroll
    for (int off = 32; off; off >>= 1) {
        sumA += __shfl_xor(sumA, off);
        pvA  += __shfl_xor(pvA, off);
        sumB += __shfl_xor(sumB, off);
        pvB  += __shfl_xor(pvB, off);
    }

    const float vbarA = pvA * __builtin_amdgcn_rcpf(sumA);
    const float vbarB = pvB * __builtin_amdgcn_rcpf(sumB);
    attended[(size_t)rowA * N_ + lane] = fmaf(vbarA, w_l, b_l);
    attended[(size_t)rowB * N_ + lane] = fmaf(vbarB, w_l, b_l);

    // Fold normalization into the exponent: w = exp2(c1*K - m2')
    const float m2pA = m2A + __builtin_amdgcn_logf(sumA);  // v_log_f32 = log2
    const float m2pB = m2B + __builtin_amdgcn_logf(sumB);

    // ---- pure store stream: fma -> exp2 -> dwordx4, 16 stores back-to-back ----
    f32x4* wrowA = reinterpret_cast<f32x4*>(weights + (size_t)rowA * L_);
    f32x4* wrowB = reinterpret_cast<f32x4*>(weights + (size_t)rowB * L_);
    #pragma unroll
    for (int i = 0; i < 8; ++i) {
        f32x4 o;
        o.x = __builtin_amdgcn_exp2f(fmaf(c1A, kk[i].x, -m2pA));
        o.y = __builtin_amdgcn_exp2f(fmaf(c1A, kk[i].y, -m2pA));
        o.z = __builtin_amdgcn_exp2f(fmaf(c1A, kk[i].z, -m2pA));
        o.w = __builtin_amdgcn_exp2f(fmaf(c1A, kk[i].w, -m2pA));
        wrowA[lane + 64 * i] = o;
    }
    #pragma unroll
    for (int i = 0; i < 8; ++i) {
        f32x4 o;
        o.x = __builtin_amdgcn_exp2f(fmaf(c1B, kk[i].x, -m2pB));
        o.y = __builtin_amdgcn_exp2f(fmaf(c1B, kk[i].y, -m2pB));
        o.z = __builtin_amdgcn_exp2f(fmaf(c1B, kk[i].z, -m2pB));
        o.w = __builtin_amdgcn_exp2f(fmaf(c1B, kk[i].w, -m2pB));
        wrowB[lane + 64 * i] = o;
    }
}

extern "C" void kernel_launch(void* const* d_in, const int* in_sizes, int n_in,
                              void* d_out, int out_size, void* d_ws, size_t ws_size,
                              hipStream_t stream) {
    const float* query = (const float*)d_in[0];
    const float* key   = (const float*)d_in[1];
    const float* value = (const float*)d_in[2];
    const float* W     = (const float*)d_in[3];
    const float* bvec  = (const float*)d_in[4];

    float* attended = (float*)d_out;                          // [B,L,N]
    float* weights  = (float*)d_out + (size_t)B_ * L_ * N_;   // [B,L,L]

    attn_all<<<dim3(B_ * (L_ / RPB)), THREADS, 0, stream>>>(
        query, key, value, W, bvec, attended, weights);
}